// Round 3
// baseline (2193.247 us; speedup 1.0000x reference)
//
#include <hip/hip_runtime.h>
#include <math.h>

#define H 64
#define IN_DIM 4800
#define DEPTH 14
#define NNODES ((1 << DEPTH) - 1)   // 16383
#define NWAVES 1024                 // tree kernel: 256 blocks x 4 waves

typedef __attribute__((ext_vector_type(8))) short short8;
typedef __attribute__((ext_vector_type(4))) float f32x4;

// ---------------- split W into bf16 hi/lo planes ----------------
__global__ void convert_w(const float* __restrict__ W, ushort* __restrict__ Wh,
                          ushort* __restrict__ Wl, int n4)
{
    int i = blockIdx.x * blockDim.x + threadIdx.x;
    if (i >= n4) return;
    float4 v = *(const float4*)&W[i * 4];
    float xs[4] = {v.x, v.y, v.z, v.w};
    ushort hv[4], lv[4];
#pragma unroll
    for (int j = 0; j < 4; ++j) {
        unsigned xb = __float_as_uint(xs[j]);
        hv[j] = (ushort)(xb >> 16);
        float r = xs[j] - __uint_as_float(xb & 0xFFFF0000u);
        lv[j] = (ushort)(__float_as_uint(r) >> 16);
    }
    *(ushort4*)&Wh[i * 4] = make_ushort4(hv[0], hv[1], hv[2], hv[3]);
    *(ushort4*)&Wl[i * 4] = make_ushort4(lv[0], lv[1], lv[2], lv[3]);
}

// ---------------- GEMM: Wx = inputs @ Wx_w.T + Wx_b  (split-bf16 MFMA) ----
// BM=64, BN=64 -> grid (4,256)=1024 blocks -> 4 blocks/CU (occupancy fix)
#define BM 64
#define BN 64
#define BK 32
#define NT (IN_DIM / BK)   // 150

__global__ __launch_bounds__(256, 4) void gemm_split(
    const float* __restrict__ A,
    const ushort* __restrict__ Bh, const ushort* __restrict__ Bl,
    const float* __restrict__ bias, float* __restrict__ C)
{
    __shared__ ushort Ah_s[BM][BK];   // 4 KB
    __shared__ ushort Al_s[BM][BK];   // 4 KB
    __shared__ ushort Bh_s[BN][BK];   // 4 KB
    __shared__ ushort Bl_s[BN][BK];   // 4 KB

    const int tid  = threadIdx.x;
    const int wave = tid >> 6, lane = tid & 63;
    const int wm = wave >> 1, wn = wave & 1;       // 2x2 wave grid
    const int m0 = blockIdx.y * BM;
    const int n0 = blockIdx.x * BN;

    // A staging: 8 consecutive floats per thread: row=tid>>2, col=(tid&3)*8
    const int ar = tid >> 2, ac = (tid & 3) * 8;
    const int aRowC = (m0 + ar < NNODES) ? (m0 + ar) : (NNODES - 1);
    const float* aPtr = A + (size_t)aRowC * IN_DIM + ac;
    // B staging: 1 chunk of 8 bf16 per plane per thread
    const int br = tid >> 2, bc = (tid & 3) * 8;
    const ushort* bhPtr = Bh + (size_t)(n0 + br) * IN_DIM + bc;
    const ushort* blPtr = Bl + (size_t)(n0 + br) * IN_DIM + bc;

    f32x4 acc[2][2] = {};

    float4 a_reg0, a_reg1;
    short8 bh_reg0, bl_reg0;

#define LOAD_TILE(t)                                                          \
    {                                                                         \
        const int k0 = (t) * BK;                                              \
        a_reg0 = *(const float4*)(aPtr + k0);                                 \
        a_reg1 = *(const float4*)(aPtr + k0 + 4);                             \
        bh_reg0 = *(const short8*)(bhPtr + k0);                               \
        bl_reg0 = *(const short8*)(blPtr + k0);                               \
    }

#define WRITE_TILE()                                                          \
    {                                                                         \
        float xs[8] = {a_reg0.x, a_reg0.y, a_reg0.z, a_reg0.w,                \
                       a_reg1.x, a_reg1.y, a_reg1.z, a_reg1.w};               \
        short8 hv, lv;                                                        \
        _Pragma("unroll")                                                     \
        for (int j = 0; j < 8; ++j) {                                         \
            unsigned xb = __float_as_uint(xs[j]);                             \
            hv[j] = (short)(xb >> 16);                                        \
            float r = xs[j] - __uint_as_float(xb & 0xFFFF0000u);              \
            lv[j] = (short)(__float_as_uint(r) >> 16);                        \
        }                                                                     \
        *(short8*)&Ah_s[ar][ac] = hv;                                         \
        *(short8*)&Al_s[ar][ac] = lv;                                         \
        *(short8*)&Bh_s[br][bc] = bh_reg0;                                    \
        *(short8*)&Bl_s[br][bc] = bl_reg0;                                    \
    }

    LOAD_TILE(0);
    WRITE_TILE();
    __syncthreads();

    const int fr = lane & 15, kg = (lane >> 4) * 8;

    for (int t = 0; t < NT; ++t) {
        if (t + 1 < NT) LOAD_TILE(t + 1);   // prefetch next tile into regs

        short8 ah[2], al[2], bh[2], bl[2];
#pragma unroll
        for (int mf = 0; mf < 2; ++mf) {
            int r = wm * 32 + mf * 16 + fr;
            ah[mf] = *(const short8*)&Ah_s[r][kg];
            al[mf] = *(const short8*)&Al_s[r][kg];
        }
#pragma unroll
        for (int nf = 0; nf < 2; ++nf) {
            int r = wn * 32 + nf * 16 + fr;
            bh[nf] = *(const short8*)&Bh_s[r][kg];
            bl[nf] = *(const short8*)&Bl_s[r][kg];
        }
#pragma unroll
        for (int mf = 0; mf < 2; ++mf)
#pragma unroll
            for (int nf = 0; nf < 2; ++nf) {
                acc[mf][nf] = __builtin_amdgcn_mfma_f32_16x16x32_bf16(ah[mf], bh[nf], acc[mf][nf], 0, 0, 0);
                acc[mf][nf] = __builtin_amdgcn_mfma_f32_16x16x32_bf16(ah[mf], bl[nf], acc[mf][nf], 0, 0, 0);
                acc[mf][nf] = __builtin_amdgcn_mfma_f32_16x16x32_bf16(al[mf], bh[nf], acc[mf][nf], 0, 0, 0);
            }
        __syncthreads();
        if (t + 1 < NT) { WRITE_TILE(); __syncthreads(); }
    }

    // epilogue: C/D layout col = lane&15, row = (lane>>4)*4 + reg
    const int rquad = (lane >> 4) * 4;
#pragma unroll
    for (int nf = 0; nf < 2; ++nf) {
        int n = n0 + wn * 32 + nf * 16 + fr;
        float bv = bias[n];
#pragma unroll
        for (int mf = 0; mf < 2; ++mf) {
            int mbase = m0 + wm * 32 + mf * 16 + rquad;
#pragma unroll
            for (int j = 0; j < 4; ++j) {
                int m = mbase + j;
                if (m < NNODES)
                    C[(size_t)m * 256 + n] = acc[mf][nf][j] + bv;
            }
        }
    }
#undef LOAD_TILE
#undef WRITE_TILE
}

// ---------------- barrier init ----------------
__global__ void init_bar(unsigned* bar) { bar[0] = 0u; bar[1] = 0u; }

// ---------------- fused tree sweep: one persistent kernel ----------------
__device__ __forceinline__ float sigmoidf_(float x) { return 1.0f / (1.0f + expf(-x)); }

__device__ __forceinline__ void grid_sync(unsigned* count, unsigned* gen)
{
    __threadfence();          // release h/c writes device-wide
    __syncthreads();
    if (threadIdx.x == 0) {
        unsigned g = __hip_atomic_load(gen, __ATOMIC_RELAXED, __HIP_MEMORY_SCOPE_AGENT);
        unsigned old = __hip_atomic_fetch_add(count, 1u, __ATOMIC_ACQ_REL, __HIP_MEMORY_SCOPE_AGENT);
        if (old == gridDim.x - 1) {
            __hip_atomic_store(count, 0u, __ATOMIC_RELAXED, __HIP_MEMORY_SCOPE_AGENT);
            __hip_atomic_fetch_add(gen, 1u, __ATOMIC_RELEASE, __HIP_MEMORY_SCOPE_AGENT);
        } else {
            while (__hip_atomic_load(gen, __ATOMIC_ACQUIRE, __HIP_MEMORY_SCOPE_AGENT) == g)
                __builtin_amdgcn_s_sleep(2);
        }
    }
    __syncthreads();
    __threadfence();          // acquire: invalidate caches before reading children
}

__global__ __launch_bounds__(256, 1) void tree_kernel(
    const float* __restrict__ Wx,
    const float* __restrict__ convW,   // [64][2][64]
    const float* __restrict__ conv_b,  // [64]
    const float* __restrict__ Ui, const float* __restrict__ Uf,
    const float* __restrict__ Uo, const float* __restrict__ Uu,  // [64][64]
    float* __restrict__ harr, float* __restrict__ carr,
    float* __restrict__ out, unsigned* __restrict__ bar)
{
    __shared__ float sh[4][192];  // per wave: hl[64] | hr[64] | avg[64]
    const int wave = threadIdx.x >> 6;
    const int lane = threadIdx.x & 63;
    const int gw = blockIdx.x * 4 + wave;   // 0..1023

    // Leaf constants: avg = conv_b for every leaf, so avg@U.T is one fixed vector.
    float cli = 0.f, clo = 0.f, clu = 0.f;
#pragma unroll
    for (int t4 = 0; t4 < 16; ++t4) {
        float4 cb = *(const float4*)&conv_b[t4 * 4];
        float4 wi = *(const float4*)&Ui[lane * 64 + t4 * 4];
        float4 wo = *(const float4*)&Uo[lane * 64 + t4 * 4];
        float4 wu = *(const float4*)&Uu[lane * 64 + t4 * 4];
        cli += wi.x * cb.x + wi.y * cb.y + wi.z * cb.z + wi.w * cb.w;
        clo += wo.x * cb.x + wo.y * cb.y + wo.z * cb.z + wo.w * cb.w;
        clu += wu.x * cb.x + wu.y * cb.y + wu.z * cb.z + wu.w * cb.w;
    }

    // ---- leaf level (d = DEPTH-1): pure elementwise ----
    {
        const int n = 1 << (DEPTH - 1), base = n - 1;   // 8192, 8191
        for (int node = gw; node < n; node += NWAVES) {
            int idx = base + node;
            float xi = Wx[idx * 256 + lane];
            float xo = Wx[idx * 256 + 128 + lane];
            float xu = Wx[idx * 256 + 192 + lane];
            float iv = sigmoidf_(xi + cli);
            float ov = sigmoidf_(xo + clo);
            float uv = tanhf(xu + clu);
            float cv = iv * uv;
            float hv = ov * tanhf(cv);
            harr[idx * 64 + lane] = hv;
            carr[idx * 64 + lane] = cv;
        }
    }

    // ---- internal levels ----
    for (int d = DEPTH - 2; d >= 0; --d) {
        grid_sync(&bar[0], &bar[1]);
        const int n = 1 << d, base = n - 1;
        for (int node = gw; node < n; node += NWAVES) {
            int idx = base + node;
            float xi = Wx[idx * 256 + lane];
            float xf = Wx[idx * 256 + 64 + lane];
            float xo = Wx[idx * 256 + 128 + lane];
            float xu = Wx[idx * 256 + 192 + lane];
            int li = 2 * idx + 1, ri = 2 * idx + 2;
            float cl = carr[li * 64 + lane];
            float cr = carr[ri * 64 + lane];
            sh[wave][lane]      = harr[li * 64 + lane];
            sh[wave][64 + lane] = harr[ri * 64 + lane];
            // wave-local LDS RAW: compiler inserts lgkmcnt waits
            float avg = conv_b[lane], fa_l = 0.f, fa_r = 0.f;
#pragma unroll
            for (int t4 = 0; t4 < 16; ++t4) {
                float4 vl = *(const float4*)&sh[wave][t4 * 4];
                float4 vr = *(const float4*)&sh[wave][64 + t4 * 4];
                float4 w0 = *(const float4*)&convW[lane * 128 + t4 * 4];
                float4 w1 = *(const float4*)&convW[lane * 128 + 64 + t4 * 4];
                float4 uf = *(const float4*)&Uf[lane * 64 + t4 * 4];
                avg  += w0.x * vl.x + w0.y * vl.y + w0.z * vl.z + w0.w * vl.w;
                avg  += w1.x * vr.x + w1.y * vr.y + w1.z * vr.z + w1.w * vr.w;
                fa_l += uf.x * vl.x + uf.y * vl.y + uf.z * vl.z + uf.w * vl.w;
                fa_r += uf.x * vr.x + uf.y * vr.y + uf.z * vr.z + uf.w * vr.w;
            }
            float fl = sigmoidf_(xf + fa_l);
            float fr = sigmoidf_(xf + fa_r);
            float sumf = fl * cl + fr * cr;

            sh[wave][128 + lane] = avg;
            float ai = 0.f, ao = 0.f, au = 0.f;
#pragma unroll
            for (int t4 = 0; t4 < 16; ++t4) {
                float4 v  = *(const float4*)&sh[wave][128 + t4 * 4];
                float4 wi = *(const float4*)&Ui[lane * 64 + t4 * 4];
                float4 wo = *(const float4*)&Uo[lane * 64 + t4 * 4];
                float4 wu = *(const float4*)&Uu[lane * 64 + t4 * 4];
                ai += wi.x * v.x + wi.y * v.y + wi.z * v.z + wi.w * v.w;
                ao += wo.x * v.x + wo.y * v.y + wo.z * v.z + wo.w * v.w;
                au += wu.x * v.x + wu.y * v.y + wu.z * v.z + wu.w * v.w;
            }
            float iv = sigmoidf_(xi + ai);
            float ov = sigmoidf_(xo + ao);
            float uv = tanhf(xu + au);
            float cv = sumf + iv * uv;
            float hv = ov * tanhf(cv);
            harr[idx * 64 + lane] = hv;
            carr[idx * 64 + lane] = cv;
            if (idx == 0) {          // root: write output directly
                out[lane] = hv;
                out[64 + lane] = cv;
            }
        }
    }
}

extern "C" void kernel_launch(void* const* d_in, const int* in_sizes, int n_in,
                              void* d_out, int out_size, void* d_ws, size_t ws_size,
                              hipStream_t stream)
{
    const float* inputs = (const float*)d_in[0];
    const float* Wx_w   = (const float*)d_in[1];
    const float* Wx_b   = (const float*)d_in[2];
    const float* Ui     = (const float*)d_in[3];
    const float* Uf     = (const float*)d_in[4];
    const float* Uo     = (const float*)d_in[5];
    const float* Uu     = (const float*)d_in[6];
    const float* convW  = (const float*)d_in[7];
    const float* conv_b = (const float*)d_in[8];

    // workspace layout (MiB offsets)
    float*    Wx  = (float*)d_ws;                                    // 16.0 MiB
    float*    h   = (float*)((char*)d_ws + (size_t)(16u << 20));     // 4 MiB
    float*    c   = (float*)((char*)d_ws + (size_t)(20u << 20));     // 4 MiB
    ushort*   Wh  = (ushort*)((char*)d_ws + (size_t)(24u << 20));    // 2.4 MiB
    ushort*   Wl  = (ushort*)((char*)d_ws + (size_t)(27u << 20));    // 2.4 MiB
    unsigned* bar = (unsigned*)((char*)d_ws + (size_t)(30u << 20));  // 8 B

    init_bar<<<1, 1, 0, stream>>>(bar);
    convert_w<<<1200, 256, 0, stream>>>(Wx_w, Wh, Wl, 307200);

    dim3 ggrid(1, 256);
    ggrid.x = 256 / BN * 4 / 4;  // = 4 N-tiles of 64
    ggrid.x = 4;
    gemm_split<<<dim3(4, 256), 256, 0, stream>>>(inputs, Wh, Wl, Wx_b, Wx);

    tree_kernel<<<256, 256, 0, stream>>>(Wx, convW, conv_b, Ui, Uf, Uo, Uu,
                                         h, c, (float*)d_out, bar);
}

// Round 6
// 1175.324 us; speedup vs baseline: 1.8661x; 1.8661x over previous
//
#include <hip/hip_runtime.h>
#include <math.h>

#define H 64
#define IN_DIM 4800
#define DEPTH 14
#define NNODES ((1 << DEPTH) - 1)   // 16383

typedef __attribute__((ext_vector_type(8))) short short8;
typedef __attribute__((ext_vector_type(4))) float f32x4;

// ---------------- split W into bf16 hi/lo planes ----------------
__global__ void convert_w(const float* __restrict__ W, ushort* __restrict__ Wh,
                          ushort* __restrict__ Wl, int n4)
{
    int i = blockIdx.x * blockDim.x + threadIdx.x;
    if (i >= n4) return;
    float4 v = *(const float4*)&W[i * 4];
    float xs[4] = {v.x, v.y, v.z, v.w};
    ushort hv[4], lv[4];
#pragma unroll
    for (int j = 0; j < 4; ++j) {
        unsigned xb = __float_as_uint(xs[j]);
        hv[j] = (ushort)(xb >> 16);
        float r = xs[j] - __uint_as_float(xb & 0xFFFF0000u);
        lv[j] = (ushort)(__float_as_uint(r) >> 16);
    }
    *(ushort4*)&Wh[i * 4] = make_ushort4(hv[0], hv[1], hv[2], hv[3]);
    *(ushort4*)&Wl[i * 4] = make_ushort4(lv[0], lv[1], lv[2], lv[3]);
}

// ---------------- GEMM: Wx = inputs @ Wx_w.T + Wx_b  (split-bf16 MFMA) ----
#define BM 64
#define BN 64
#define BK 32
#define NT (IN_DIM / BK)   // 150

// XOR swizzle: row r (64 B/row of ushort[32]), kc = 16B-aligned byte column.
// Bijective per row; fragment reads (stride-64B rows) become <=2-way (free).
#define SWZB(r, kc) (((r) << 6) + ((kc) ^ ((((r) >> 1) & 3) << 4)))

__global__ __launch_bounds__(256, 4) void gemm_split(
    const float* __restrict__ A,
    const ushort* __restrict__ Bh, const ushort* __restrict__ Bl,
    const float* __restrict__ bias, float* __restrict__ C)
{
    __shared__ ushort Ah_s[BM * BK];   // 4 KB each
    __shared__ ushort Al_s[BM * BK];
    __shared__ ushort Bh_s[BN * BK];
    __shared__ ushort Bl_s[BN * BK];

    const int tid  = threadIdx.x;
    const int wave = tid >> 6, lane = tid & 63;
    const int wm = wave >> 1, wn = wave & 1;       // 2x2 wave grid
    const int m0 = blockIdx.y * BM;
    const int n0 = blockIdx.x * BN;

    // staging: row = tid>>2 (0..63), col chunk = (tid&3)*8 elems
    const int ar = tid >> 2;
    const int c8 = (tid & 3) * 8;
    const int aRowC = (m0 + ar < NNODES) ? (m0 + ar) : (NNODES - 1);
    const float*  aPtr  = A  + (size_t)aRowC * IN_DIM + c8;
    const ushort* bhPtr = Bh + (size_t)(n0 + ar) * IN_DIM + c8;
    const ushort* blPtr = Bl + (size_t)(n0 + ar) * IN_DIM + c8;

    char* AhB = (char*)Ah_s;  char* AlB = (char*)Al_s;
    char* BhB = (char*)Bh_s;  char* BlB = (char*)Bl_s;

    const int wofs = SWZB(ar, c8 * 2);            // staging write offset (bytes)

    const int fr = lane & 15, kc = (lane >> 4) * 16;  // fragment row / byte col
    int aro[2], bro[2];
#pragma unroll
    for (int i = 0; i < 2; ++i) {
        aro[i] = SWZB(wm * 32 + i * 16 + fr, kc);
        bro[i] = SWZB(wn * 32 + i * 16 + fr, kc);
    }

    f32x4 acc[2][2] = {};
    float4 a_reg0, a_reg1;
    short8 bh_reg0, bl_reg0;

#define LOAD_TILE(t)                                                          \
    {                                                                         \
        const int k0 = (t) * BK;                                              \
        a_reg0 = *(const float4*)(aPtr + k0);                                 \
        a_reg1 = *(const float4*)(aPtr + k0 + 4);                             \
        bh_reg0 = *(const short8*)(bhPtr + k0);                               \
        bl_reg0 = *(const short8*)(blPtr + k0);                               \
    }

#define WRITE_TILE()                                                          \
    {                                                                         \
        float xs[8] = {a_reg0.x, a_reg0.y, a_reg0.z, a_reg0.w,                \
                       a_reg1.x, a_reg1.y, a_reg1.z, a_reg1.w};               \
        short8 hv, lv;                                                        \
        _Pragma("unroll")                                                     \
        for (int j = 0; j < 8; ++j) {                                         \
            unsigned xb = __float_as_uint(xs[j]);                             \
            hv[j] = (short)(xb >> 16);                                        \
            float r = xs[j] - __uint_as_float(xb & 0xFFFF0000u);              \
            lv[j] = (short)(__float_as_uint(r) >> 16);                        \
        }                                                                     \
        *(short8*)(AhB + wofs) = hv;                                          \
        *(short8*)(AlB + wofs) = lv;                                          \
        *(short8*)(BhB + wofs) = bh_reg0;                                     \
        *(short8*)(BlB + wofs) = bl_reg0;                                     \
    }

    LOAD_TILE(0);
    WRITE_TILE();
    __syncthreads();

    for (int t = 0; t < NT; ++t) {
        if (t + 1 < NT) LOAD_TILE(t + 1);   // prefetch next tile into regs

        short8 ah[2], al[2], bh[2], bl[2];
#pragma unroll
        for (int i = 0; i < 2; ++i) {
            ah[i] = *(const short8*)(AhB + aro[i]);
            al[i] = *(const short8*)(AlB + aro[i]);
            bh[i] = *(const short8*)(BhB + bro[i]);
            bl[i] = *(const short8*)(BlB + bro[i]);
        }
#pragma unroll
        for (int mf = 0; mf < 2; ++mf)
#pragma unroll
            for (int nf = 0; nf < 2; ++nf) {
                acc[mf][nf] = __builtin_amdgcn_mfma_f32_16x16x32_bf16(ah[mf], bh[nf], acc[mf][nf], 0, 0, 0);
                acc[mf][nf] = __builtin_amdgcn_mfma_f32_16x16x32_bf16(ah[mf], bl[nf], acc[mf][nf], 0, 0, 0);
                acc[mf][nf] = __builtin_amdgcn_mfma_f32_16x16x32_bf16(al[mf], bh[nf], acc[mf][nf], 0, 0, 0);
            }
        __syncthreads();
        if (t + 1 < NT) { WRITE_TILE(); __syncthreads(); }
    }

    // epilogue: C/D layout col = lane&15, row = (lane>>4)*4 + reg
    const int rquad = (lane >> 4) * 4;
#pragma unroll
    for (int nf = 0; nf < 2; ++nf) {
        int n = n0 + wn * 32 + nf * 16 + fr;
        float bv = bias[n];
#pragma unroll
        for (int mf = 0; mf < 2; ++mf) {
            int mbase = m0 + wm * 32 + mf * 16 + rquad;
#pragma unroll
            for (int j = 0; j < 4; ++j) {
                int m = mbase + j;
                if (m < NNODES)
                    C[(size_t)m * 256 + n] = acc[mf][nf][j] + bv;
            }
        }
    }
#undef LOAD_TILE
#undef WRITE_TILE
}

// ---------------- tree sweep ----------------
__device__ __forceinline__ float sigmoidf_(float x) { return 1.0f / (1.0f + expf(-x)); }

// per-lane weight row (64 floats) dot vector (64 floats)
__device__ __forceinline__ float rowdot(const float* __restrict__ Wrow,
                                        const float* __restrict__ vec)
{
    float s0 = 0.f, s1 = 0.f;
#pragma unroll
    for (int k = 0; k < 64; k += 4) {
        float4 w = *(const float4*)&Wrow[k];
        float4 v = *(const float4*)&vec[k];
        s0 += w.x * v.x + w.y * v.y;
        s1 += w.z * v.z + w.w * v.w;
    }
    return s0 + s1;
}

// LDS-based rowdot (avg vector lives in LDS; in-order DS unit makes the
// same-wave cross-lane write->read safe, unlike global).
__device__ __forceinline__ float rowdot_lds(const float* __restrict__ Wrow,
                                            const float* vec)
{
    float s0 = 0.f, s1 = 0.f;
#pragma unroll
    for (int k = 0; k < 64; k += 4) {
        float4 w = *(const float4*)&Wrow[k];
        float4 v = *(const float4*)&vec[k];
        s0 += w.x * v.x + w.y * v.y;
        s1 += w.z * v.z + w.w * v.w;
    }
    return s0 + s1;
}

// Levels 13..8: block b owns subtree rooted at g = 255+b. No cross-block deps.
// Level-d nodes of subtree: g = (256+b)*m + t - 1, m = 2^(d-8), t in [0,m).
__global__ __launch_bounds__(256, 1) void subtree_kernel(
    const float* __restrict__ Wx,
    const float* __restrict__ convW, const float* __restrict__ conv_b,
    const float* __restrict__ Ui, const float* __restrict__ Uf,
    const float* __restrict__ Uo, const float* __restrict__ Uu,
    float* __restrict__ harr, float* __restrict__ carr)
{
    __shared__ float sh_avg[4][4][64];   // [wave][slot][lane] = 4 KB
    const int wave = threadIdx.x >> 6, lane = threadIdx.x & 63;
    const int b = blockIdx.x;

    // leaf constants: avg = conv_b for every leaf
    const float cli = rowdot(&Ui[lane * 64], conv_b);
    const float clo = rowdot(&Uo[lane * 64], conv_b);
    const float clu = rowdot(&Uu[lane * 64], conv_b);

    // ---- leaves (d=13): elementwise ----
    for (int t = wave; t < 32; t += 4) {
        int g = (256 + b) * 32 + t - 1;
        float xi = Wx[g * 256 + lane];
        float xo = Wx[g * 256 + 128 + lane];
        float xu = Wx[g * 256 + 192 + lane];
        float iv = sigmoidf_(xi + cli);
        float ov = sigmoidf_(xo + clo);
        float uv = tanhf(xu + clu);
        float cv = iv * uv;
        harr[g * 64 + lane] = ov * tanhf(cv);
        carr[g * 64 + lane] = cv;
    }
    __syncthreads();

    // ---- internal levels d=12..8 (m = 16..1), phase-split for L1 reuse ----
    for (int m = 16; m >= 1; m >>= 1) {
        for (int t = wave; t < m; t += 4) {              // pass A: conv -> avg (LDS)
            int g = (256 + b) * m + t - 1;
            int gl = 2 * g + 1, gr = 2 * g + 2;
            sh_avg[wave][t >> 2][lane] = conv_b[lane]
                + rowdot(&convW[lane * 128],      &harr[gl * 64])
                + rowdot(&convW[lane * 128 + 64], &harr[gr * 64]);
        }
        for (int t = wave; t < m; t += 4) {              // pass B: Uf -> sumf
            int g = (256 + b) * m + t - 1;
            int gl = 2 * g + 1, gr = 2 * g + 2;
            float xf = Wx[g * 256 + 64 + lane];
            float fl = sigmoidf_(xf + rowdot(&Uf[lane * 64], &harr[gl * 64]));
            float fr = sigmoidf_(xf + rowdot(&Uf[lane * 64], &harr[gr * 64]));
            carr[g * 64 + lane] = fl * carr[gl * 64 + lane] + fr * carr[gr * 64 + lane];
        }
        for (int t = wave; t < m; t += 4) {              // pass C: Uu+Ui -> c
            int g = (256 + b) * m + t - 1;
            const float* av = sh_avg[wave][t >> 2];
            float xi = Wx[g * 256 + lane];
            float xu = Wx[g * 256 + 192 + lane];
            float uv = tanhf(xu + rowdot_lds(&Uu[lane * 64], av));
            float iv = sigmoidf_(xi + rowdot_lds(&Ui[lane * 64], av));
            carr[g * 64 + lane] += iv * uv;
        }
        for (int t = wave; t < m; t += 4) {              // pass D: Uo -> h
            int g = (256 + b) * m + t - 1;
            const float* av = sh_avg[wave][t >> 2];
            float xo = Wx[g * 256 + 128 + lane];
            float ov = sigmoidf_(xo + rowdot_lds(&Uo[lane * 64], av));
            harr[g * 64 + lane] = ov * tanhf(carr[g * 64 + lane]);
        }
        __syncthreads();
    }
}

// Levels 7..0 (255 nodes): ONE block, 8 waves; block-local syncs only.
__global__ __launch_bounds__(512, 1) void top_kernel(
    const float* __restrict__ Wx,
    const float* __restrict__ convW, const float* __restrict__ conv_b,
    const float* __restrict__ Ui, const float* __restrict__ Uf,
    const float* __restrict__ Uo, const float* __restrict__ Uu,
    float* __restrict__ harr, float* __restrict__ carr,
    float* __restrict__ out)
{
    __shared__ float sh_avg[8][16][64];  // [wave][slot][lane] = 32 KB
    const int wave = threadIdx.x >> 6, lane = threadIdx.x & 63;

    for (int m = 128; m >= 1; m >>= 1) {                 // d = 7..0
        for (int t = wave; t < m; t += 8) {              // pass A
            int g = m - 1 + t;
            int gl = 2 * g + 1, gr = 2 * g + 2;
            sh_avg[wave][t >> 3][lane] = conv_b[lane]
                + rowdot(&convW[lane * 128],      &harr[gl * 64])
                + rowdot(&convW[lane * 128 + 64], &harr[gr * 64]);
        }
        for (int t = wave; t < m; t += 8) {              // pass B
            int g = m - 1 + t;
            int gl = 2 * g + 1, gr = 2 * g + 2;
            float xf = Wx[g * 256 + 64 + lane];
            float fl = sigmoidf_(xf + rowdot(&Uf[lane * 64], &harr[gl * 64]));
            float fr = sigmoidf_(xf + rowdot(&Uf[lane * 64], &harr[gr * 64]));
            carr[g * 64 + lane] = fl * carr[gl * 64 + lane] + fr * carr[gr * 64 + lane];
        }
        for (int t = wave; t < m; t += 8) {              // pass C
            int g = m - 1 + t;
            const float* av = sh_avg[wave][t >> 3];
            float xi = Wx[g * 256 + lane];
            float xu = Wx[g * 256 + 192 + lane];
            float uv = tanhf(xu + rowdot_lds(&Uu[lane * 64], av));
            float iv = sigmoidf_(xi + rowdot_lds(&Ui[lane * 64], av));
            float cv = carr[g * 64 + lane] + iv * uv;
            carr[g * 64 + lane] = cv;
            if (g == 0) out[64 + lane] = cv;
        }
        for (int t = wave; t < m; t += 8) {              // pass D
            int g = m - 1 + t;
            const float* av = sh_avg[wave][t >> 3];
            float xo = Wx[g * 256 + 128 + lane];
            float ov = sigmoidf_(xo + rowdot_lds(&Uo[lane * 64], av));
            float hv = ov * tanhf(carr[g * 64 + lane]);
            harr[g * 64 + lane] = hv;
            if (g == 0) out[lane] = hv;
        }
        __syncthreads();
    }
}

extern "C" void kernel_launch(void* const* d_in, const int* in_sizes, int n_in,
                              void* d_out, int out_size, void* d_ws, size_t ws_size,
                              hipStream_t stream)
{
    const float* inputs = (const float*)d_in[0];
    const float* Wx_w   = (const float*)d_in[1];
    const float* Wx_b   = (const float*)d_in[2];
    const float* Ui     = (const float*)d_in[3];
    const float* Uf     = (const float*)d_in[4];
    const float* Uo     = (const float*)d_in[5];
    const float* Uu     = (const float*)d_in[6];
    const float* convW  = (const float*)d_in[7];
    const float* conv_b = (const float*)d_in[8];

    // workspace layout (byte offsets)
    float*  Wx    = (float*)d_ws;                                   // 16.8 MiB
    float*  harr  = (float*)((char*)d_ws + (size_t)(17u << 20));    // 4.2 MiB
    float*  carr  = (float*)((char*)d_ws + (size_t)(22u << 20));    // 4.2 MiB
    ushort* Wh    = (ushort*)((char*)d_ws + (size_t)(27u << 20));   // 2.4 MiB
    ushort* Wl    = (ushort*)((char*)d_ws + (size_t)(30u << 20));   // 2.4 MiB

    convert_w<<<1200, 256, 0, stream>>>(Wx_w, Wh, Wl, 307200);

    gemm_split<<<dim3(4, 256), 256, 0, stream>>>(inputs, Wh, Wl, Wx_b, Wx);

    subtree_kernel<<<256, 256, 0, stream>>>(Wx, convW, conv_b, Ui, Uf, Uo, Uu,
                                            harr, carr);

    top_kernel<<<1, 512, 0, stream>>>(Wx, convW, conv_b, Ui, Uf, Uo, Uu,
                                      harr, carr, (float*)d_out);
}